// Round 7
// baseline (131.280 us; speedup 1.0000x reference)
//
#include <hip/hip_runtime.h>

#define IMG_H 512
#define IMG_W 512
#define NGAUSS 10000
#define N_VIEWS 4
#define PATCH 40

// -2 * ln(0.001): g > 0.001  <=>  q < QMAX (the -10 clip only shrinks g further)
#define QMAX 13.815511f

// Block = (view, 8-row band). 4 views x 64 bands = 256 blocks = 1 per CU.
// 1024 threads = 16 waves/CU. Phase 2 is owner-computes: 32 threads per
// 16x8 sub-tile, 4 pixels per thread, register accumulation, ZERO atomics
// on image data (R6's LDS-atomic serialization was the ~30 us sink).
#define BLOCK_T 1024
#define BAND_ROWS 8
#define NBANDS_IMG (IMG_H / BAND_ROWS)        // 64
#define NBLOCKS (N_VIEWS * NBANDS_IMG)        // 256
#define NSUB 32                               // 16-col sub-tiles per band
#define QCAP 1300                             // band survivor queue; hot band ~1035
#define CAP_ST 256                            // per-sub-tile list; hot ~150

__device__ __forceinline__ float fast_sigmoid(float x) {
    return 1.0f / (1.0f + __expf(-x));
}

// Single kernel, single graph node, NO workspace, NO global atomics, NO LDS
// image. Per block (view, 8-row band):
//   phase 1: scan all splats of the view; exact validity (Zc,u,v); per-splat
//            radius UPPER BOUND rub = sqrt(QMAX*exp(max ls)) + 0.5 (since
//            a,dd = sum R_ij^2 s_j <= max s_j) -> superset row/col window;
//            append to band queue + overlapped 16-col sub-tile lists.
//   phase 2: prep params for each queued survivor into LDS (once).
//   phase 3: 32 threads per sub-tile, 4 px each: for each listed survivor,
//            EXACT column reject (min_dy q = dx^2*(i00*i11-i01^2)/i11 > QMAX
//            => g <= 0.001 for the whole column), else evaluate 4 pixels with
//            the exact reference mask (g>0.001 ∧ PATCH box), accumulate in
//            registers, then plain-store the owned pixels.
// Rows are partitioned exactly across blocks -> each out pixel written once.
__global__ __launch_bounds__(BLOCK_T) void gs_band_kernel(
    const float* __restrict__ poses,
    const float* __restrict__ Km,
    const float* __restrict__ means,
    const float* __restrict__ log_scales,
    const float* __restrict__ quats,
    const float* __restrict__ shs,
    const float* __restrict__ opac,
    float* __restrict__ out)
{
    __shared__ float4 s_p0[QCAP];                 // uvx uvy i00 i01   (20800 B)
    __shared__ float4 s_p1[QCAP];                 // i11 w0  w1  w2    (20800 B)
    __shared__ int    s_qid[QCAP];                // splat id          ( 5200 B)
    __shared__ unsigned short s_list[NSUB * CAP_ST]; //                (16384 B)
    __shared__ int    s_ln[NSUB];
    __shared__ int    s_qn;                       // total 63316 B < 64 KB

    const int view = blockIdx.x >> 6;
    const int y0   = (blockIdx.x & 63) << 3;      // first row of this band
    const int tid  = threadIdx.x;

    if (tid < NSUB) s_ln[tid] = 0;
    if (tid == 0) s_qn = 0;
    __syncthreads();

    // wave-uniform camera constants (scalar loads)
    const float* P = poses + view * 16;
    const float P0 = P[0], P1 = P[1], P2  = P[2],  P3  = P[3];
    const float P4 = P[4], P5 = P[5], P6  = P[6],  P7  = P[7];
    const float P8 = P[8], P9 = P[9], P10 = P[10], P11 = P[11];
    const float K0 = Km[0], K1 = Km[1], K2 = Km[2];
    const float K3 = Km[3], K4 = Km[4], K5 = Km[5];
    const float K6 = Km[6], K7 = Km[7], K8 = Km[8];

    // ---- phase 1: scan all splats of this view ----
    for (int n = tid; n < NGAUSS; n += BLOCK_T) {
        const float m0 = means[n * 3 + 0];
        const float m1 = means[n * 3 + 1];
        const float m2 = means[n * 3 + 2];

        const float Xc = P0 * m0 + P1 * m1 + P2  * m2 + P3;
        const float Yc = P4 * m0 + P5 * m1 + P6  * m2 + P7;
        const float Zc = P8 * m0 + P9 * m1 + P10 * m2 + P11;

        const float ppx = K0 * Xc + K1 * Yc + K2 * Zc;
        const float ppy = K3 * Xc + K4 * Yc + K5 * Zc;
        const float ppz = K6 * Xc + K7 * Yc + K8 * Zc;

        const float rcp = 1.0f / (ppz + 1e-8f);
        const float uvx = ppx * rcp;
        const float uvy = ppy * rcp;

        const int u = (int)uvx;   // trunc, matches jnp.trunc + int32 cast
        const int v = (int)uvy;

        if (!((Zc >= 0.1f) && (u >= 0) && (u < IMG_W) && (v >= 0) && (v < IMG_H)))
            continue;             // exact validity (same test as reference)

        // superset radius: a,dd <= exp(max log_scale)
        const float ls0 = log_scales[n * 3 + 0];
        const float ls1 = log_scales[n * 3 + 1];
        const float ls2 = log_scales[n * 3 + 2];
        const float rub = sqrtf(QMAX * __expf(fmaxf(fmaxf(ls0, ls1), ls2))) + 0.5f;

        const int ylo = max((int)ceilf (uvy - rub), max(v - PATCH / 2, 0));
        const int yhi = min((int)floorf(uvy + rub), min(v + PATCH / 2 - 1, IMG_H - 1));
        if (ylo > yhi || ylo > y0 + (BAND_ROWS - 1) || yhi < y0)
            continue;                                   // no overlap with band

        const int xlo = max((int)ceilf (uvx - rub), max(u - PATCH / 2, 0));
        const int xhi = min((int)floorf(uvx + rub), min(u + PATCH / 2 - 1, IMG_W - 1));
        if (xlo > xhi) continue;

        const int qidx = atomicAdd(&s_qn, 1);
        if (qidx >= QCAP) continue;                     // overflow would fail bench visibly
        s_qid[qidx] = n;

        const int st0 = xlo >> 4, st1 = xhi >> 4;       // 1..2 sub-tiles (window ~4-6 px)
        for (int st = st0; st <= st1; ++st) {
            const int li = atomicAdd(&s_ln[st], 1);
            if (li < CAP_ST) s_list[st * CAP_ST + li] = (unsigned short)qidx;
        }
    }
    __syncthreads();

    const int qn = min(s_qn, QCAP);

    // ---- phase 2: materialize params for each survivor (once per block) ----
    for (int i = tid; i < qn; i += BLOCK_T) {
        const int n = s_qid[i];

        const float m0 = means[n * 3 + 0];
        const float m1 = means[n * 3 + 1];
        const float m2 = means[n * 3 + 2];

        const float4 qv = *reinterpret_cast<const float4*>(quats + n * 4);
        const float qw = qv.x, qx = qv.y, qy = qv.z, qz = qv.w;
        const float R00 = 1.0f - 2.0f * (qy * qy + qz * qz);
        const float R01 = 2.0f * (qx * qy - qw * qz);
        const float R02 = 2.0f * (qx * qz + qw * qy);
        const float R10 = 2.0f * (qx * qy + qw * qz);
        const float R11 = 1.0f - 2.0f * (qx * qx + qz * qz);
        const float R12 = 2.0f * (qy * qz - qw * qx);

        const float s0 = __expf(log_scales[n * 3 + 0]);
        const float s1 = __expf(log_scales[n * 3 + 1]);
        const float s2 = __expf(log_scales[n * 3 + 2]);

        const float a  = R00 * R00 * s0 + R01 * R01 * s1 + R02 * R02 * s2;
        const float b  = R00 * R10 * s0 + R01 * R11 * s1 + R02 * R12 * s2;
        const float dd = R10 * R10 * s0 + R11 * R11 * s1 + R12 * R12 * s2;

        const float det = a * dd - b * b;
        const float i00 =  dd / det;
        const float i01 = -b  / det;
        const float i11 =  a  / det;

        const float op = fast_sigmoid(opac[n]);
        const float w0 = op * fast_sigmoid(shs[n * 48 +  0]);
        const float w1 = op * fast_sigmoid(shs[n * 48 + 16]);
        const float w2 = op * fast_sigmoid(shs[n * 48 + 32]);

        const float Xc = P0 * m0 + P1 * m1 + P2  * m2 + P3;
        const float Yc = P4 * m0 + P5 * m1 + P6  * m2 + P7;
        const float Zc = P8 * m0 + P9 * m1 + P10 * m2 + P11;
        const float ppx = K0 * Xc + K1 * Yc + K2 * Zc;
        const float ppy = K3 * Xc + K4 * Yc + K5 * Zc;
        const float ppz = K6 * Xc + K7 * Yc + K8 * Zc;
        const float rcp = 1.0f / (ppz + 1e-8f);

        s_p0[i] = make_float4(ppx * rcp, ppy * rcp, i00, i01);
        s_p1[i] = make_float4(i11, w0, w1, w2);
    }
    __syncthreads();

    // ---- phase 3: owner-computes eval, register accumulation ----
    const int st   = tid >> 5;                     // sub-tile 0..31
    const int l    = tid & 31;
    const int col  = (st << 4) + (l & 15);         // owned column
    const int rsel = l >> 4;                       // 0/1: rows rsel, rsel+2, +4, +6
    const float fx = (float)col;

    float accR[4] = {0.f, 0.f, 0.f, 0.f};
    float accG[4] = {0.f, 0.f, 0.f, 0.f};
    float accB[4] = {0.f, 0.f, 0.f, 0.f};

    const int ln = min(s_ln[st], CAP_ST);
    for (int k = 0; k < ln; ++k) {
        const int qi = s_list[st * CAP_ST + k];
        const float4 p0 = s_p0[qi];                // 32-lane broadcast
        const float4 p1 = s_p1[qi];

        const float dx   = fx - p0.x;
        const float det2 = p0.z * p1.x - p0.w * p0.w;   // i00*i11 - i01^2 > 0
        // exact column reject: min over dy of q is dx^2*det2/i11
        if (dx * dx * det2 >= QMAX * p1.x) continue;

        const int u = (int)p0.x;
        const int v = (int)p0.y;
        const bool colok = (col >= u - PATCH / 2) & (col <= u + PATCH / 2 - 1);

        const float A = p0.z * dx * dx;
        const float B = 2.0f * p0.w * dx;

        #pragma unroll
        for (int r = 0; r < 4; ++r) {
            const int py = y0 + rsel + (r << 1);
            const float dy = (float)py - p0.y;
            const float q  = A + dy * (B + p1.x * dy);
            const float g  = __expf(fminf(fmaxf(-0.5f * q, -10.0f), 0.0f));
            const bool ok = colok & (g > 0.001f)
                          & (py >= v - PATCH / 2) & (py <= v + PATCH / 2 - 1);
            if (ok) {
                accR[r] += g * p1.y;
                accG[r] += g * p1.z;
                accB[r] += g * p1.w;
            }
        }
    }

    // ---- store owned pixels (each written exactly once across the grid) ----
    #pragma unroll
    for (int r = 0; r < 4; ++r) {
        const int py = y0 + rsel + (r << 1);
        float* o = out + (((size_t)view * IMG_H + py) * IMG_W + col) * 3;
        o[0] = accR[r]; o[1] = accG[r]; o[2] = accB[r];
    }
}

extern "C" void kernel_launch(void* const* d_in, const int* in_sizes, int n_in,
                              void* d_out, int out_size, void* d_ws, size_t ws_size,
                              hipStream_t stream) {
    const float* poses      = (const float*)d_in[0];
    const float* intrinsics = (const float*)d_in[1];
    const float* means      = (const float*)d_in[2];
    const float* log_scales = (const float*)d_in[3];
    const float* quats      = (const float*)d_in[4];
    const float* shs        = (const float*)d_in[5];
    const float* opac       = (const float*)d_in[6];
    float* out = (float*)d_out;

    // ONE kernel node, no workspace, no global atomics, no LDS atomics on data.
    gs_band_kernel<<<NBLOCKS, BLOCK_T, 0, stream>>>(
        poses, intrinsics, means, log_scales, quats, shs, opac, out);
}